// Round 1
// baseline (216.797 us; speedup 1.0000x reference)
//
#include <hip/hip_runtime.h>
#include <math.h>

#define B_ 8
#define T_ 64
#define N_ 196
#define D_ 768
#define K_ 8
#define FEAT 40
#define EPSF 1e-6f

constexpr int    ROWS  = B_ * T_ * N_;              // 100352
constexpr int    BN    = B_ * N_;                   // 1568
constexpr int    TASKS = BN * K_;                   // 12544
constexpr long long HSIZE = (long long)ROWS * D_;   // 77070336

// ---- workspace layout (floats) ----
constexpr size_t WS_V     = 0;                       // [B,N,K,T] = 802816
constexpr size_t WS_FEATS = 802816;                  // [BN,40]   = 62720
constexpr size_t WS_Y     = 865536;                  // [BN,D]    = 1204224
constexpr size_t WS_BETAS = 2069760;                 // [D]       = 768

__device__ __forceinline__ float wredux(float v) {
#pragma unroll
    for (int off = 32; off > 0; off >>= 1)
        v += __shfl_xor(v, off, 64);
    return v;
}

// Kernel 1: v[b,n,k,t] = mask[b,t,n] * dot(x[b,t,n,:], proj_W[k,:])
// One wave per row, proj_W cached in registers (96 VGPRs), grid-stride.
__global__ __launch_bounds__(256) void k_proj(const float* __restrict__ x,
                                              const float* __restrict__ mask,
                                              const float* __restrict__ pw,
                                              float* __restrict__ v_ws,
                                              int totalWaves) {
    const int lane = threadIdx.x & 63;
    const int gw   = blockIdx.x * (blockDim.x >> 6) + (threadIdx.x >> 6);

    float4 u[3][8];
#pragma unroll
    for (int i = 0; i < 3; i++)
#pragma unroll
        for (int k = 0; k < 8; k++)
            u[i][k] = *(const float4*)(pw + k * D_ + i * 256 + lane * 4);

    for (int r = gw; r < ROWS; r += totalWaves) {
        const float4* xr = (const float4*)(x + (size_t)r * D_);
        float4 xa = xr[lane];
        float4 xb = xr[lane + 64];
        float4 xc = xr[lane + 128];
        float acc[8];
#pragma unroll
        for (int k = 0; k < 8; k++) {
            float a;
            a  = xa.x * u[0][k].x + xa.y * u[0][k].y + xa.z * u[0][k].z + xa.w * u[0][k].w;
            a += xb.x * u[1][k].x + xb.y * u[1][k].y + xb.z * u[1][k].z + xb.w * u[1][k].w;
            a += xc.x * u[2][k].x + xc.y * u[2][k].y + xc.z * u[2][k].z + xc.w * u[2][k].w;
            acc[k] = wredux(a);
        }
        float m = mask[r];
        float val = acc[0];
#pragma unroll
        for (int k = 1; k < 8; k++)
            val = ((lane & 7) == k) ? acc[k] : val;
        if (lane < 8) {
            int b   = r / (T_ * N_);
            int rem = r - b * (T_ * N_);
            int t   = rem / N_;
            int n   = rem - t * N_;
            v_ws[(((size_t)(b * N_ + n)) * K_ + lane) * T_ + t] = val * m;
        }
    }
}

// Kernel 2: per (b,n,k): rms over T -> bounded tanh -> DCT coeffs + mean + rms
// One wave per task, lane = t.
__global__ __launch_bounds__(256) void k_feat(const float* __restrict__ v_ws,
                                              float* __restrict__ feats) {
    const int lane = threadIdx.x & 63;
    const int task = blockIdx.x * 4 + (threadIdx.x >> 6);
    if (task >= TASKS) return;

    float vv  = v_ws[(size_t)task * T_ + lane];
    float s2  = wredux(vv * vv);
    float rms = sqrtf(s2 * (1.0f / T_) + EPSF);
    float vb  = 2.5f * tanhf(vv / (rms + EPSF));

    const float PI = 3.14159265358979323846f;
    float ph = PI * ((float)lane + 0.5f) / (float)T_;
    float c1 = cosf(ph);
    float c2 = cosf(2.0f * ph);

    float n1  = wredux(c1 * c1);
    float n2  = wredux(c2 * c2);
    float S1  = wredux(vb);
    float Sc1 = wredux(vb * c1);
    float Sc2 = wredux(vb * c2);
    float Sq  = wredux(vb * vb);

    if (lane == 0) {
        float* o = feats + (size_t)task * 5;
        o[0] = S1 / (8.0f + EPSF);               // basis row 0: ones, ||.||=8
        o[1] = Sc1 / (sqrtf(n1) + EPSF);
        o[2] = Sc2 / (sqrtf(n2) + EPSF);
        o[3] = S1 * (1.0f / T_);
        o[4] = sqrtf(Sq * (1.0f / T_) + EPSF);
    }
}

// Kernel 3: W = softplus(W_raw) -> d_out tail;  beta_s = sigmoid(beta) -> ws
__global__ __launch_bounds__(256) void k_wsp(const float* __restrict__ wraw,
                                             const float* __restrict__ beta,
                                             float* __restrict__ wout,
                                             float* __restrict__ beta_s) {
    int i = blockIdx.x * blockDim.x + threadIdx.x;
    if (i < FEAT * D_) {
        float xw = wraw[i];
        wout[i] = fmaxf(xw, 0.0f) + log1pf(expf(-fabsf(xw)));
    }
    if (i < D_) beta_s[i] = 1.0f / (1.0f + expf(-beta[i]));
}

// Kernel 4: y[bn,:] = feats[bn,:] @ W   ([1568,40] x [40,768])
__global__ __launch_bounds__(256) void k_gemm(const float* __restrict__ feats,
                                              const float* __restrict__ W,
                                              float* __restrict__ y) {
    __shared__ float sf[FEAT];
    const int bn  = blockIdx.x;
    const int tid = threadIdx.x;
    if (tid < FEAT) sf[tid] = feats[(size_t)bn * FEAT + tid];
    __syncthreads();
    float a0 = 0.f, a1 = 0.f, a2 = 0.f;
#pragma unroll
    for (int f = 0; f < FEAT; f++) {
        float s = sf[f];
        const float* wr = W + (size_t)f * D_;
        a0 += s * wr[tid];
        a1 += s * wr[tid + 256];
        a2 += s * wr[tid + 512];
    }
    float* yr = y + (size_t)bn * D_;
    yr[tid]       = a0;
    yr[tid + 256] = a1;
    yr[tid + 512] = a2;
}

// Kernel 5: h = x + mask * beta_s * y   (identical to m*h+(1-m)*x for h=x+bs*y)
__global__ __launch_bounds__(192) void k_final(const float* __restrict__ x,
                                               const float* __restrict__ maskv,
                                               const float* __restrict__ y,
                                               const float* __restrict__ beta_s,
                                               float* __restrict__ h) {
    const int n   = blockIdx.x;
    const int t   = blockIdx.y;
    const int b   = blockIdx.z;
    const int tid = threadIdx.x;
    const size_t row = ((size_t)b * T_ + t) * N_ + n;
    float m = maskv[row];
    const float4* xr = (const float4*)(x + row * (size_t)D_);
    const float4* yr = (const float4*)(y + ((size_t)b * N_ + n) * D_);
    const float4* br = (const float4*)beta_s;
    float4 xv = xr[tid];
    float4 yv = yr[tid];
    float4 bv = br[tid];
    float4 hv;
    hv.x = xv.x + m * bv.x * yv.x;
    hv.y = xv.y + m * bv.y * yv.y;
    hv.z = xv.z + m * bv.z * yv.z;
    hv.w = xv.w + m * bv.w * yv.w;
    *(float4*)(h + row * (size_t)D_ + (size_t)tid * 4) = hv;
}

extern "C" void kernel_launch(void* const* d_in, const int* in_sizes, int n_in,
                              void* d_out, int out_size, void* d_ws, size_t ws_size,
                              hipStream_t stream) {
    const float* x    = (const float*)d_in[0];
    const float* mask = (const float*)d_in[1];
    const float* pw   = (const float*)d_in[2];
    const float* wraw = (const float*)d_in[3];
    const float* beta = (const float*)d_in[4];

    float* h    = (float*)d_out;
    float* wout = h + HSIZE;

    float* ws     = (float*)d_ws;
    float* v_ws   = ws + WS_V;
    float* feats  = ws + WS_FEATS;
    float* y      = ws + WS_Y;
    float* beta_s = ws + WS_BETAS;

    const int blocks1    = 2048;
    const int totalWaves = blocks1 * 4;
    hipLaunchKernelGGL(k_proj, dim3(blocks1), dim3(256), 0, stream,
                       x, mask, pw, v_ws, totalWaves);
    hipLaunchKernelGGL(k_feat, dim3((TASKS + 3) / 4), dim3(256), 0, stream,
                       v_ws, feats);
    hipLaunchKernelGGL(k_wsp, dim3((FEAT * D_ + 255) / 256), dim3(256), 0, stream,
                       wraw, beta, wout, beta_s);
    hipLaunchKernelGGL(k_gemm, dim3(BN), dim3(256), 0, stream,
                       feats, wout, y);
    hipLaunchKernelGGL(k_final, dim3(N_, T_, B_), dim3(192), 0, stream,
                       x, mask, y, beta_s, h);
}